// Round 1
// 68.115 us; speedup vs baseline: 1.0469x; 1.0469x over previous
//
#include <hip/hip_runtime.h>
#include <math.h>

// Problem constants (fixed by the reference)
#define B_ 512
#define K_ 1024
#define D_ 256
#define EPS_ 1e-6f

// MFMA rewrite: dt = x.p and xa = x.a are two GEMMs (M=512, N=1024, K=256, NT
// layout) -> run them on the matrix cores with split-bf16 operands.
//   v = hi + lo (both bf16_rne)  ->  dt ~= xh.ph + xh.pl + xl.ph  (drop xl.pl ~ 2^-18)
// Per-(b,k) scalars x2/p2/a2/pa are accumulated in exact fp32 during staging.
//
// Tiling: BM=64 (b) x BN=32 (k), BK=32, 512 threads = 8 waves as 4m x 2n,
// 16x16 output per wave, 6 x mfma_f32_16x16x32_bf16 per wave per K-step.
// Grid (32, 8) = 256 blocks = 1 block/CU, 2 waves/SIMD.
// LDS rows padded to 40 bf16 (80 B = 5 x 16 B): fragment ds_read_b128 chunk
// index = 5*row + kgroup -> 64 distinct chunks, bank-balanced (no conflicts).
#define BM 64
#define BN 32
#define BK 32
#define STR 40

using short8  = __attribute__((ext_vector_type(8))) short;
using floatx4 = __attribute__((ext_vector_type(4))) float;

__device__ __forceinline__ unsigned short f2bf(float f) {
    unsigned int u = __float_as_uint(f);
    u += 0x7FFFu + ((u >> 16) & 1u);          // round-to-nearest-even
    return (unsigned short)(u >> 16);
}
__device__ __forceinline__ float bf2f(unsigned short h) {
    return __uint_as_float((unsigned int)h << 16);
}

__global__ __launch_bounds__(512) void hyp_mlr_mfma(
    const float* __restrict__ x,   // [B, D]
    const float* __restrict__ p,   // [K, D]
    const float* __restrict__ a,   // [K, D]
    float* __restrict__ out)       // [B, K]
{
    __shared__ __align__(16) unsigned short Xh[2][BM][STR];
    __shared__ __align__(16) unsigned short Xl[2][BM][STR];
    __shared__ __align__(16) unsigned short Ph[2][BN][STR];
    __shared__ __align__(16) unsigned short Pl[2][BN][STR];
    __shared__ __align__(16) unsigned short Ah[2][BN][STR];
    __shared__ __align__(16) unsigned short Al[2][BN][STR];
    __shared__ float  x2s[BM];
    __shared__ float4 scal[BN];    // (p2, pa, na, beta)

    const int t    = threadIdx.x;
    const int lane = t & 63;
    const int wave = t >> 6;
    const int k0   = blockIdx.x * BN;
    const int b0   = blockIdx.y * BM;

    // ---- staging roles: waves 0-3 stage x (8 elems/thr), waves 4-7 stage p&a (4+4) ----
    const bool isx = (t < 256);
    int srow, scol;
    const float *gp0, *gp1;
    if (isx) {
        srow = t >> 2; scol = (t & 3) * 8;
        gp0 = x + (b0 + srow) * D_ + scol;
        gp1 = gp0 + 4;
    } else {
        const int q = t - 256;
        srow = q >> 3; scol = (q & 7) * 4;
        gp0 = p + (k0 + srow) * D_ + scol;
        gp1 = a + (k0 + srow) * D_ + scol;
    }

    float s0 = 0.f, s1 = 0.f, s2 = 0.f;   // x2 | p2, a2, pa (exact fp32)

    auto cvt_store = [&](int buf, float4 v0, float4 v1) {
        if (isx) {
            float e[8] = {v0.x, v0.y, v0.z, v0.w, v1.x, v1.y, v1.z, v1.w};
            unsigned int hp[4], lp[4];
#pragma unroll
            for (int j = 0; j < 4; ++j) {
                const float e0 = e[2 * j], e1 = e[2 * j + 1];
                const unsigned short h0 = f2bf(e0), h1 = f2bf(e1);
                hp[j] = (unsigned int)h0 | ((unsigned int)h1 << 16);
                lp[j] = (unsigned int)f2bf(e0 - bf2f(h0))
                      | ((unsigned int)f2bf(e1 - bf2f(h1)) << 16);
                s0 = fmaf(e0, e0, fmaf(e1, e1, s0));
            }
            *(uint4*)&Xh[buf][srow][scol] = make_uint4(hp[0], hp[1], hp[2], hp[3]);
            *(uint4*)&Xl[buf][srow][scol] = make_uint4(lp[0], lp[1], lp[2], lp[3]);
        } else {
            float ep[4] = {v0.x, v0.y, v0.z, v0.w};
            float ea[4] = {v1.x, v1.y, v1.z, v1.w};
            unsigned int hp[2], lp[2], ha[2], la[2];
#pragma unroll
            for (int j = 0; j < 2; ++j) {
                const float pe0 = ep[2 * j], pe1 = ep[2 * j + 1];
                const float ae0 = ea[2 * j], ae1 = ea[2 * j + 1];
                const unsigned short hp0 = f2bf(pe0), hp1 = f2bf(pe1);
                const unsigned short ha0 = f2bf(ae0), ha1 = f2bf(ae1);
                hp[j] = (unsigned int)hp0 | ((unsigned int)hp1 << 16);
                lp[j] = (unsigned int)f2bf(pe0 - bf2f(hp0))
                      | ((unsigned int)f2bf(pe1 - bf2f(hp1)) << 16);
                ha[j] = (unsigned int)ha0 | ((unsigned int)ha1 << 16);
                la[j] = (unsigned int)f2bf(ae0 - bf2f(ha0))
                      | ((unsigned int)f2bf(ae1 - bf2f(ha1)) << 16);
                s0 = fmaf(pe0, pe0, fmaf(pe1, pe1, s0));
                s1 = fmaf(ae0, ae0, fmaf(ae1, ae1, s1));
                s2 = fmaf(pe0, ae0, fmaf(pe1, ae1, s2));
            }
            *(uint2*)&Ph[buf][srow][scol] = make_uint2(hp[0], hp[1]);
            *(uint2*)&Pl[buf][srow][scol] = make_uint2(lp[0], lp[1]);
            *(uint2*)&Ah[buf][srow][scol] = make_uint2(ha[0], ha[1]);
            *(uint2*)&Al[buf][srow][scol] = make_uint2(la[0], la[1]);
        }
    };

    // ---- MFMA geometry: wave (wm, wn) owns 16x16 tile at (wm*16, wn*16) ----
    const int wm = wave & 3, wn = wave >> 2;
    const int m0 = wm * 16, n0 = wn * 16;
    const int lr = lane & 15, lg = lane >> 4;

    floatx4 accD = {0.f, 0.f, 0.f, 0.f};   // x . p
    floatx4 accA = {0.f, 0.f, 0.f, 0.f};   // x . a

    // ---- prologue ----
    cvt_store(0, *(const float4*)gp0, *(const float4*)gp1);
    __syncthreads();

    int buf = 0;
#pragma unroll
    for (int s = 0; s < D_ / BK; ++s) {
        float4 nv0, nv1;
        if (s < D_ / BK - 1) {
            nv0 = *(const float4*)(gp0 + (s + 1) * BK);
            nv1 = *(const float4*)(gp1 + (s + 1) * BK);
        }

        const short8 xh = *(const short8*)&Xh[buf][m0 + lr][lg * 8];
        const short8 xl = *(const short8*)&Xl[buf][m0 + lr][lg * 8];
        const short8 ph = *(const short8*)&Ph[buf][n0 + lr][lg * 8];
        const short8 pl = *(const short8*)&Pl[buf][n0 + lr][lg * 8];
        const short8 ah = *(const short8*)&Ah[buf][n0 + lr][lg * 8];
        const short8 al = *(const short8*)&Al[buf][n0 + lr][lg * 8];
        accD = __builtin_amdgcn_mfma_f32_16x16x32_bf16(xh, ph, accD, 0, 0, 0);
        accA = __builtin_amdgcn_mfma_f32_16x16x32_bf16(xh, ah, accA, 0, 0, 0);
        accD = __builtin_amdgcn_mfma_f32_16x16x32_bf16(xh, pl, accD, 0, 0, 0);
        accA = __builtin_amdgcn_mfma_f32_16x16x32_bf16(xh, al, accA, 0, 0, 0);
        accD = __builtin_amdgcn_mfma_f32_16x16x32_bf16(xl, ph, accD, 0, 0, 0);
        accA = __builtin_amdgcn_mfma_f32_16x16x32_bf16(xl, ah, accA, 0, 0, 0);

        if (s < D_ / BK - 1) cvt_store(buf ^ 1, nv0, nv1);
        __syncthreads();
        buf ^= 1;
    }

    // ---- publish per-row / per-col scalars ----
    if (isx) {
        s0 += __shfl_xor(s0, 1);
        s0 += __shfl_xor(s0, 2);
        if ((t & 3) == 0) x2s[srow] = s0;
    } else {
        s0 += __shfl_xor(s0, 1); s0 += __shfl_xor(s0, 2); s0 += __shfl_xor(s0, 4);
        s1 += __shfl_xor(s1, 1); s1 += __shfl_xor(s1, 2); s1 += __shfl_xor(s1, 4);
        s2 += __shfl_xor(s2, 1); s2 += __shfl_xor(s2, 2); s2 += __shfl_xor(s2, 4);
        if (((t - 256) & 7) == 0) {
            const float beta = 1.f - s0;
            scal[srow] = make_float4(s0, s2, beta * sqrtf(s1), beta);
        }
    }
    __syncthreads();

    // ---- epilogue: Ganea hyperbolic MLR logit from the 6 scalars ----
    // C/D layout (m89): col = lane&15, row = (lane>>4)*4 + reg
    const float4 sc  = scal[n0 + lr];       // p2, pa, na, beta
    const float  lam = 2.f / (sc.w + EPS_);
#pragma unroll
    for (int i = 0; i < 4; ++i) {
        const int   r    = m0 + lg * 4 + i;
        const float x2v  = x2s[r];
        const float dt   = accD[i];
        const float xa   = accA[i];
        const float alpha = 1.f + x2v - 2.f * dt;
        const float rg    = 1.f / (1.f - 2.f * dt + sc.x * x2v + EPS_);
        const float z2    = (alpha * alpha * sc.x - 2.f * alpha * sc.w * dt
                             + sc.w * sc.w * x2v) * rg * rg;
        const float za    = sc.w * (sc.w * xa - alpha * sc.y) * rg;
        const float arg   = 2.f * za / ((1.f - z2) * sc.z + EPS_);
        out[(b0 + r) * K_ + k0 + n0 + lr] = lam * sc.z * asinhf(arg);
    }
}

extern "C" void kernel_launch(void* const* d_in, const int* in_sizes, int n_in,
                              void* d_out, int out_size, void* d_ws, size_t ws_size,
                              hipStream_t stream) {
    const float* x = (const float*)d_in[0];  // [512, 256]
    const float* p = (const float*)d_in[1];  // [1024, 256]
    const float* a = (const float*)d_in[2];  // [1024, 256]
    float* out = (float*)d_out;              // [512, 1024]

    dim3 grid(K_ / BN, B_ / BM);   // (32, 8) = 256 blocks, 1/CU
    dim3 block(512);               // 8 waves
    hyp_mlr_mfma<<<grid, block, 0, stream>>>(x, p, a, out);
}

// Round 2
// 66.117 us; speedup vs baseline: 1.0785x; 1.0302x over previous
//
#include <hip/hip_runtime.h>
#include <math.h>

// Problem constants (fixed by the reference)
#define B_ 512
#define K_ 1024
#define D_ 256
#define EPS_ 1e-6f

// Single-phase MFMA kernel: K=256 fits LDS entirely, so stage once -> one
// barrier -> 32 ds_read_b128 + 32 MFMA -> epilogue. No double buffer, no
// per-step barriers.
//   dt = x.p, xa = x.a via mfma_f32_16x16x32_bf16 with split-bf16 x
//   (x = xh + xl, both bf16_rne) and SINGLE-bf16 p/a (|p|,|a| ~ 1e-3, so
//   dropping their low halves adds ~5e-6 to logits vs current absmax 3e-5).
// Row scalars x2/p2/a2/pa accumulated in exact fp32 during staging, combined
// via small LDS partial arrays (no shuffle phase, covered by the one barrier).
//
// Tiling: BM=64 (b) x BN=32 (k) per block, 512 threads = 8 waves as 4m x 2n,
// 16x16 output tile per wave. Grid (32, 8) = 256 blocks = 1 block/CU.
// LDS layout: [row][256] bf16, rows 512 B; 16B chunk c stored at c ^ (row&7)
// -> fragment ds_read_b128 (16 lanes same k-group, rows 0..15) spreads 8
// lanes x 16 B per bank-quad = conflict-free minimum. Same for b128 writes
// (64 lanes = 64 rows, fixed chunk).
#define BM 64
#define BN 32

using short8  = __attribute__((ext_vector_type(8))) short;
using floatx4 = __attribute__((ext_vector_type(4))) float;

static __device__ __forceinline__ unsigned short f2bf(float f) {
    unsigned int u = __float_as_uint(f);
    u += 0x7FFFu + ((u >> 16) & 1u);          // round-to-nearest-even
    return (unsigned short)(u >> 16);
}
static __device__ __forceinline__ float bf2f(unsigned short h) {
    return __uint_as_float((unsigned int)h << 16);
}

__global__ __launch_bounds__(512) void hyp_mlr_mfma(
    const float* __restrict__ x,   // [B, D]
    const float* __restrict__ p,   // [K, D]
    const float* __restrict__ a,   // [K, D]
    float* __restrict__ out)       // [B, K]
{
    __shared__ __align__(16) unsigned short XhL[BM * 256];  // 32 KB
    __shared__ __align__(16) unsigned short XlL[BM * 256];  // 32 KB
    __shared__ __align__(16) unsigned short PL [BN * 256];  // 16 KB
    __shared__ __align__(16) unsigned short AL [BN * 256];  // 16 KB
    __shared__ __align__(16) float Sx [BM][4];              // x2 partials
    __shared__ __align__(16) float Sp [BN][8];              // p2 partials
    __shared__ __align__(16) float Sa [BN][8];              // a2 partials
    __shared__ __align__(16) float Spa[BN][8];              // p.a partials

    const int t  = threadIdx.x;
    const int k0 = blockIdx.x * BN;
    const int b0 = blockIdx.y * BM;

    // ---- staging: waves 0-3 stage x (split hi/lo), waves 4-7 stage p & a ----
    if (t < 256) {
        const int row = t & 63;
        const int cq  = t >> 6;                 // 0..3
        const float* g = x + (b0 + row) * D_;
        float s0 = 0.f;
#pragma unroll
        for (int i = 0; i < 8; ++i) {
            const int c = cq + 4 * i;           // 16B chunk 0..31
            const float4 v0 = *(const float4*)(g + c * 8);
            const float4 v1 = *(const float4*)(g + c * 8 + 4);
            const float e[8] = {v0.x, v0.y, v0.z, v0.w, v1.x, v1.y, v1.z, v1.w};
            unsigned int hp[4], lp[4];
#pragma unroll
            for (int j = 0; j < 4; ++j) {
                const float e0 = e[2 * j], e1 = e[2 * j + 1];
                const unsigned short h0 = f2bf(e0), h1 = f2bf(e1);
                hp[j] = (unsigned int)h0 | ((unsigned int)h1 << 16);
                lp[j] = (unsigned int)f2bf(e0 - bf2f(h0))
                      | ((unsigned int)f2bf(e1 - bf2f(h1)) << 16);
                s0 = fmaf(e0, e0, fmaf(e1, e1, s0));
            }
            const int idx = row * 256 + ((c ^ (row & 7)) << 3);
            *(uint4*)&XhL[idx] = make_uint4(hp[0], hp[1], hp[2], hp[3]);
            *(uint4*)&XlL[idx] = make_uint4(lp[0], lp[1], lp[2], lp[3]);
        }
        Sx[row][cq] = s0;
    } else {
        const int q   = t - 256;
        const int row = q & 31;
        const int cq  = q >> 5;                 // 0..7
        const float* gp = p + (k0 + row) * D_;
        const float* ga = a + (k0 + row) * D_;
        float sp2 = 0.f, sa2 = 0.f, spa = 0.f;
#pragma unroll
        for (int i = 0; i < 4; ++i) {
            const int c = cq + 8 * i;           // 16B chunk 0..31
            const float4 p0 = *(const float4*)(gp + c * 8);
            const float4 p1 = *(const float4*)(gp + c * 8 + 4);
            const float4 a0 = *(const float4*)(ga + c * 8);
            const float4 a1 = *(const float4*)(ga + c * 8 + 4);
            const float ep[8] = {p0.x, p0.y, p0.z, p0.w, p1.x, p1.y, p1.z, p1.w};
            const float ea[8] = {a0.x, a0.y, a0.z, a0.w, a1.x, a1.y, a1.z, a1.w};
            unsigned int wp[4], wa[4];
#pragma unroll
            for (int j = 0; j < 4; ++j) {
                const float pe0 = ep[2 * j], pe1 = ep[2 * j + 1];
                const float ae0 = ea[2 * j], ae1 = ea[2 * j + 1];
                wp[j] = (unsigned int)f2bf(pe0) | ((unsigned int)f2bf(pe1) << 16);
                wa[j] = (unsigned int)f2bf(ae0) | ((unsigned int)f2bf(ae1) << 16);
                sp2 = fmaf(pe0, pe0, fmaf(pe1, pe1, sp2));
                sa2 = fmaf(ae0, ae0, fmaf(ae1, ae1, sa2));
                spa = fmaf(pe0, ae0, fmaf(pe1, ae1, spa));
            }
            const int idx = row * 256 + ((c ^ (row & 7)) << 3);
            *(uint4*)&PL[idx] = make_uint4(wp[0], wp[1], wp[2], wp[3]);
            *(uint4*)&AL[idx] = make_uint4(wa[0], wa[1], wa[2], wa[3]);
        }
        Sp [row][cq] = sp2;
        Sa [row][cq] = sa2;
        Spa[row][cq] = spa;
    }

    __syncthreads();   // the only barrier

    // ---- MFMA: wave (wm, wn) owns 16x16 tile at (wm*16, wn*16) ----
    const int lane = t & 63;
    const int wave = t >> 6;
    const int wm = wave & 3, wn = wave >> 2;
    const int m0 = wm * 16, n0 = wn * 16;
    const int lr = lane & 15, lg = lane >> 4;

    floatx4 accD = {0.f, 0.f, 0.f, 0.f};   // x . p
    floatx4 accA = {0.f, 0.f, 0.f, 0.f};   // x . a

    const int xbase = (m0 + lr) * 256;
    const int pbase = (n0 + lr) * 256;
    const int sw    = lr & 7;
#pragma unroll
    for (int ks = 0; ks < 8; ++ks) {
        const int off = ((ks * 4 + lg) ^ sw) << 3;
        const short8 xh = *(const short8*)&XhL[xbase + off];
        const short8 xl = *(const short8*)&XlL[xbase + off];
        const short8 pv = *(const short8*)&PL [pbase + off];
        const short8 av = *(const short8*)&AL [pbase + off];
        accD = __builtin_amdgcn_mfma_f32_16x16x32_bf16(xh, pv, accD, 0, 0, 0);
        accA = __builtin_amdgcn_mfma_f32_16x16x32_bf16(xh, av, accA, 0, 0, 0);
        accD = __builtin_amdgcn_mfma_f32_16x16x32_bf16(xl, pv, accD, 0, 0, 0);
        accA = __builtin_amdgcn_mfma_f32_16x16x32_bf16(xl, av, accA, 0, 0, 0);
    }

    // ---- epilogue: Ganea hyperbolic MLR logit ----
    // C/D layout (m89): col = lane&15, row = (lane>>4)*4 + reg
    const int kc = n0 + lr;
    const float4 sp0 = *(const float4*)&Sp [kc][0];
    const float4 sp1 = *(const float4*)&Sp [kc][4];
    const float4 sa0 = *(const float4*)&Sa [kc][0];
    const float4 sa1 = *(const float4*)&Sa [kc][4];
    const float4 sq0 = *(const float4*)&Spa[kc][0];
    const float4 sq1 = *(const float4*)&Spa[kc][4];
    const float p2 = (sp0.x + sp0.y) + (sp0.z + sp0.w)
                   + (sp1.x + sp1.y) + (sp1.z + sp1.w);
    const float a2 = (sa0.x + sa0.y) + (sa0.z + sa0.w)
                   + (sa1.x + sa1.y) + (sa1.z + sa1.w);
    const float pa = (sq0.x + sq0.y) + (sq0.z + sq0.w)
                   + (sq1.x + sq1.y) + (sq1.z + sq1.w);
    const float beta = 1.f - p2;
    const float na   = beta * sqrtf(a2);
    const float lam  = 2.f / (beta + EPS_);
#pragma unroll
    for (int i = 0; i < 4; ++i) {
        const int r = m0 + lg * 4 + i;
        const float4 sx = *(const float4*)&Sx[r][0];
        const float x2v = (sx.x + sx.y) + (sx.z + sx.w);
        const float dt  = accD[i];
        const float xa  = accA[i];
        const float alpha = 1.f + x2v - 2.f * dt;
        const float rg    = 1.f / (1.f - 2.f * dt + p2 * x2v + EPS_);
        const float z2    = (alpha * alpha * p2 - 2.f * alpha * beta * dt
                             + beta * beta * x2v) * rg * rg;
        const float za    = beta * (beta * xa - alpha * pa) * rg;
        const float arg   = 2.f * za / ((1.f - z2) * na + EPS_);
        out[(b0 + r) * K_ + k0 + kc] = lam * na * asinhf(arg);
    }
}

extern "C" void kernel_launch(void* const* d_in, const int* in_sizes, int n_in,
                              void* d_out, int out_size, void* d_ws, size_t ws_size,
                              hipStream_t stream) {
    const float* x = (const float*)d_in[0];  // [512, 256]
    const float* p = (const float*)d_in[1];  // [1024, 256]
    const float* a = (const float*)d_in[2];  // [1024, 256]
    float* out = (float*)d_out;              // [512, 1024]

    dim3 grid(K_ / BN, B_ / BM);   // (32, 8) = 256 blocks, 1/CU
    dim3 block(512);               // 8 waves
    hyp_mlr_mfma<<<grid, block, 0, stream>>>(x, p, a, out);
}

// Round 3
// 65.215 us; speedup vs baseline: 1.0934x; 1.0138x over previous
//
#include <hip/hip_runtime.h>
#include <math.h>

// Problem constants (fixed by the reference)
#define B_ 512
#define K_ 1024
#define D_ 256
#define EPS_ 1e-6f

// Single-phase MFMA kernel, v3: 1024 threads so staging (the dominant phase,
// fp32 -> split-bf16 conversion) is split 16-way at 4 waves/SIMD; waves 8-15
// exit after the single barrier. Global loads hoisted ahead of the convert
// loop (batched vmcnt). Library asinhf replaced with inline
// copysign(ln2 * log2(|v| + sqrt(v^2+1))) -- v_log_f32 error ~1e-7 on logit.
//
//   dt = x.p, xa = x.a via mfma_f32_16x16x32_bf16, split-bf16 x (x = xh+xl),
//   single-bf16 p/a (|p|,|a| ~ 1e-3: low halves contribute ~3e-5 max).
//   Row scalars x2/p2/a2/pa accumulated in exact fp32 during staging.
//
// Tiling: BM=64 (b) x BN=32 (k) per block, MFMA by waves 0-7 as 4m x 2n,
// 16x16 tile per wave. Grid (32, 8) = 256 blocks = 1 block/CU.
// LDS: [row][256] bf16 (512 B rows); 16B chunk c stored at c ^ (row&7) ->
// both b128 writes and fragment reads spread 8 lanes x 16 B per bank-quad
// (conflict-free minimum).
#define BM 64
#define BN 32

using short8  = __attribute__((ext_vector_type(8))) short;
using floatx4 = __attribute__((ext_vector_type(4))) float;

static __device__ __forceinline__ unsigned short f2bf(float f) {
    unsigned int u = __float_as_uint(f);
    u += 0x7FFFu + ((u >> 16) & 1u);          // round-to-nearest-even
    return (unsigned short)(u >> 16);
}
static __device__ __forceinline__ float bf2f(unsigned short h) {
    return __uint_as_float((unsigned int)h << 16);
}
static __device__ __forceinline__ float fast_asinh(float v) {
    const float s = fabsf(v);
    const float r = __log2f(s + sqrtf(fmaf(s, s, 1.f))) * 0.6931471805599453f;
    return copysignf(r, v);
}

__global__ __launch_bounds__(1024) void hyp_mlr_mfma(
    const float* __restrict__ x,   // [B, D]
    const float* __restrict__ p,   // [K, D]
    const float* __restrict__ a,   // [K, D]
    float* __restrict__ out)       // [B, K]
{
    __shared__ __align__(16) unsigned short XhL[BM * 256];  // 32 KB
    __shared__ __align__(16) unsigned short XlL[BM * 256];  // 32 KB
    __shared__ __align__(16) unsigned short PL [BN * 256];  // 16 KB
    __shared__ __align__(16) unsigned short AL [BN * 256];  // 16 KB
    __shared__ __align__(16) float Sx [BM][8];              // x2 partials
    __shared__ __align__(16) float Sp [BN][16];             // p2 partials
    __shared__ __align__(16) float Sa [BN][16];             // a2 partials
    __shared__ __align__(16) float Spa[BN][16];             // p.a partials

    const int t  = threadIdx.x;
    const int k0 = blockIdx.x * BN;
    const int b0 = blockIdx.y * BM;

    // ---- staging: threads 0-511 stage x (split hi/lo), 512-1023 stage p & a ----
    if (t < 512) {
        const int row = t & 63;
        const int cq  = t >> 6;                 // 0..7
        const float* g = x + (b0 + row) * D_;
        float4 v[8];
#pragma unroll
        for (int i = 0; i < 4; ++i) {           // hoist: issue all loads first
            const int c = cq + 8 * i;           // 16B chunk 0..31
            v[2 * i]     = *(const float4*)(g + c * 8);
            v[2 * i + 1] = *(const float4*)(g + c * 8 + 4);
        }
        float s0 = 0.f;
#pragma unroll
        for (int i = 0; i < 4; ++i) {
            const int c = cq + 8 * i;
            const float e[8] = {v[2*i].x, v[2*i].y, v[2*i].z, v[2*i].w,
                                v[2*i+1].x, v[2*i+1].y, v[2*i+1].z, v[2*i+1].w};
            unsigned int hp[4], lp[4];
#pragma unroll
            for (int j = 0; j < 4; ++j) {
                const float e0 = e[2 * j], e1 = e[2 * j + 1];
                const unsigned short h0 = f2bf(e0), h1 = f2bf(e1);
                hp[j] = (unsigned int)h0 | ((unsigned int)h1 << 16);
                lp[j] = (unsigned int)f2bf(e0 - bf2f(h0))
                      | ((unsigned int)f2bf(e1 - bf2f(h1)) << 16);
                s0 = fmaf(e0, e0, fmaf(e1, e1, s0));
            }
            const int idx = row * 256 + ((c ^ (row & 7)) << 3);
            *(uint4*)&XhL[idx] = make_uint4(hp[0], hp[1], hp[2], hp[3]);
            *(uint4*)&XlL[idx] = make_uint4(lp[0], lp[1], lp[2], lp[3]);
        }
        Sx[row][cq] = s0;
    } else {
        const int q   = t - 512;
        const int row = q & 31;
        const int cq  = q >> 5;                 // 0..15
        const float* gp = p + (k0 + row) * D_;
        const float* ga = a + (k0 + row) * D_;
        float4 pv[4], av[4];
#pragma unroll
        for (int i = 0; i < 2; ++i) {           // hoist: issue all loads first
            const int c = cq + 16 * i;          // 16B chunk 0..31
            pv[2 * i]     = *(const float4*)(gp + c * 8);
            pv[2 * i + 1] = *(const float4*)(gp + c * 8 + 4);
            av[2 * i]     = *(const float4*)(ga + c * 8);
            av[2 * i + 1] = *(const float4*)(ga + c * 8 + 4);
        }
        float sp2 = 0.f, sa2 = 0.f, spa = 0.f;
#pragma unroll
        for (int i = 0; i < 2; ++i) {
            const int c = cq + 16 * i;
            const float ep[8] = {pv[2*i].x, pv[2*i].y, pv[2*i].z, pv[2*i].w,
                                 pv[2*i+1].x, pv[2*i+1].y, pv[2*i+1].z, pv[2*i+1].w};
            const float ea[8] = {av[2*i].x, av[2*i].y, av[2*i].z, av[2*i].w,
                                 av[2*i+1].x, av[2*i+1].y, av[2*i+1].z, av[2*i+1].w};
            unsigned int wp[4], wa[4];
#pragma unroll
            for (int j = 0; j < 4; ++j) {
                const float pe0 = ep[2 * j], pe1 = ep[2 * j + 1];
                const float ae0 = ea[2 * j], ae1 = ea[2 * j + 1];
                wp[j] = (unsigned int)f2bf(pe0) | ((unsigned int)f2bf(pe1) << 16);
                wa[j] = (unsigned int)f2bf(ae0) | ((unsigned int)f2bf(ae1) << 16);
                sp2 = fmaf(pe0, pe0, fmaf(pe1, pe1, sp2));
                sa2 = fmaf(ae0, ae0, fmaf(ae1, ae1, sa2));
                spa = fmaf(pe0, ae0, fmaf(pe1, ae1, spa));
            }
            const int idx = row * 256 + ((c ^ (row & 7)) << 3);
            *(uint4*)&PL[idx] = make_uint4(wp[0], wp[1], wp[2], wp[3]);
            *(uint4*)&AL[idx] = make_uint4(wa[0], wa[1], wa[2], wa[3]);
        }
        Sp [row][cq] = sp2;
        Sa [row][cq] = sa2;
        Spa[row][cq] = spa;
    }

    __syncthreads();   // the only barrier
    if (t >= 512) return;   // waves 8-15 are staging-only

    // ---- MFMA: wave (wm, wn) owns 16x16 tile at (wm*16, wn*16) ----
    const int lane = t & 63;
    const int wave = t >> 6;                    // 0..7
    const int wm = wave & 3, wn = wave >> 2;
    const int m0 = wm * 16, n0 = wn * 16;
    const int lr = lane & 15, lg = lane >> 4;

    floatx4 accD = {0.f, 0.f, 0.f, 0.f};   // x . p
    floatx4 accA = {0.f, 0.f, 0.f, 0.f};   // x . a

    const int xbase = (m0 + lr) * 256;
    const int pbase = (n0 + lr) * 256;
    const int sw    = lr & 7;
#pragma unroll
    for (int ks = 0; ks < 8; ++ks) {
        const int off = ((ks * 4 + lg) ^ sw) << 3;
        const short8 xh = *(const short8*)&XhL[xbase + off];
        const short8 xl = *(const short8*)&XlL[xbase + off];
        const short8 pw = *(const short8*)&PL [pbase + off];
        const short8 aw = *(const short8*)&AL [pbase + off];
        accD = __builtin_amdgcn_mfma_f32_16x16x32_bf16(xh, pw, accD, 0, 0, 0);
        accA = __builtin_amdgcn_mfma_f32_16x16x32_bf16(xh, aw, accA, 0, 0, 0);
        accD = __builtin_amdgcn_mfma_f32_16x16x32_bf16(xl, pw, accD, 0, 0, 0);
        accA = __builtin_amdgcn_mfma_f32_16x16x32_bf16(xl, aw, accA, 0, 0, 0);
    }

    // ---- epilogue: Ganea hyperbolic MLR logit ----
    // C/D layout (m89): col = lane&15, row = (lane>>4)*4 + reg
    const int kc = n0 + lr;
    float p2 = 0.f, a2 = 0.f, pa = 0.f;
#pragma unroll
    for (int j = 0; j < 4; ++j) {
        const float4 q0 = *(const float4*)&Sp [kc][4 * j];
        const float4 q1 = *(const float4*)&Sa [kc][4 * j];
        const float4 q2 = *(const float4*)&Spa[kc][4 * j];
        p2 += (q0.x + q0.y) + (q0.z + q0.w);
        a2 += (q1.x + q1.y) + (q1.z + q1.w);
        pa += (q2.x + q2.y) + (q2.z + q2.w);
    }
    const float beta = 1.f - p2;
    const float na   = beta * sqrtf(a2);
    const float lam  = 2.f / (beta + EPS_);
#pragma unroll
    for (int i = 0; i < 4; ++i) {
        const int r = m0 + lg * 4 + i;
        const float4 sx0 = *(const float4*)&Sx[r][0];
        const float4 sx1 = *(const float4*)&Sx[r][4];
        const float x2v = ((sx0.x + sx0.y) + (sx0.z + sx0.w))
                        + ((sx1.x + sx1.y) + (sx1.z + sx1.w));
        const float dt  = accD[i];
        const float xa  = accA[i];
        const float alpha = 1.f + x2v - 2.f * dt;
        const float rg    = 1.f / (1.f - 2.f * dt + p2 * x2v + EPS_);
        const float z2    = (alpha * alpha * p2 - 2.f * alpha * beta * dt
                             + beta * beta * x2v) * rg * rg;
        const float za    = beta * (beta * xa - alpha * pa) * rg;
        const float arg   = 2.f * za / ((1.f - z2) * na + EPS_);
        out[(b0 + r) * K_ + k0 + kc] = lam * na * fast_asinh(arg);
    }
}

extern "C" void kernel_launch(void* const* d_in, const int* in_sizes, int n_in,
                              void* d_out, int out_size, void* d_ws, size_t ws_size,
                              hipStream_t stream) {
    const float* x = (const float*)d_in[0];  // [512, 256]
    const float* p = (const float*)d_in[1];  // [1024, 256]
    const float* a = (const float*)d_in[2];  // [1024, 256]
    float* out = (float*)d_out;              // [512, 1024]

    dim3 grid(K_ / BN, B_ / BM);   // (32, 8) = 256 blocks, 1/CU
    dim3 block(1024);              // 16 waves: all stage, waves 0-7 compute
    hyp_mlr_mfma<<<grid, block, 0, stream>>>(x, p, a, out);
}

// Round 4
// 63.831 us; speedup vs baseline: 1.1172x; 1.0217x over previous
//
#include <hip/hip_runtime.h>
#include <math.h>

// Problem constants (fixed by the reference)
#define B_ 512
#define K_ 1024
#define D_ 256
#define EPS_ 1e-6f

// Single-phase MFMA kernel, v4.
// Changes vs v3 (theory: staging convert VALU is the dominant remaining phase):
//  - fp32 -> bf16 conversion via __builtin_convertvector(float2 -> bf16x2),
//    which the compiler lowers to native v_cvt_pk_bf16_f32 (1 inst / pair vs
//    ~19 for manual RNE bit-ops hi+lo). Same RNE rounding -> absmax unchanged.
//  - Sp/Sa/Spa epilogue scratch padded to 20-float rows (bank stride 20 ->
//    <=2-way, free; was stride 16 -> 8-way conflicts on the b128 reads).
//  - MFMA accumulators split into 4 independent chains (hi/lo x D/A), summed
//    in the epilogue: removes 16-deep dependent-MFMA latency exposure at the
//    2 compute-waves/SIMD occupancy.
//
// Structure (unchanged): K=256 staged whole in LDS, one barrier, 32 ds_read
// + 32 MFMA per wave, analytic epilogue with inline asinh.
//   dt = x.p, xa = x.a via mfma_f32_16x16x32_bf16, split-bf16 x (x = xh+xl),
//   single-bf16 p/a (|p|,|a| ~ 1e-3). Row scalars x2/p2/a2/pa in exact fp32.
// Tiling: BM=64 x BN=32 per block, waves 0-7 as 4m x 2n, 16x16 per wave.
// Grid (32, 8) = 256 blocks = 1/CU; 1024 threads stage (16-way split),
// waves 8-15 exit after the barrier.
// LDS: [row][256] bf16 (512 B rows); 16B chunk c stored at c ^ (row&7) ->
// writes and fragment reads both spread 8 lanes x 16 B per bank-quad.
#define BM 64
#define BN 32

using short8   = __attribute__((ext_vector_type(8))) short;
using floatx4  = __attribute__((ext_vector_type(4))) float;
using floatx2v = __attribute__((ext_vector_type(2))) float;
using bf16x2   = __attribute__((ext_vector_type(2))) __bf16;

static __device__ __forceinline__ unsigned int pk_bf16(float e0, float e1) {
    floatx2v f = {e0, e1};
    return __builtin_bit_cast(unsigned int, __builtin_convertvector(f, bf16x2));
}
static __device__ __forceinline__ float fast_asinh(float v) {
    const float s = fabsf(v);
    const float r = __log2f(s + sqrtf(fmaf(s, s, 1.f))) * 0.6931471805599453f;
    return copysignf(r, v);
}

__global__ __launch_bounds__(1024) void hyp_mlr_mfma(
    const float* __restrict__ x,   // [B, D]
    const float* __restrict__ p,   // [K, D]
    const float* __restrict__ a,   // [K, D]
    float* __restrict__ out)       // [B, K]
{
    __shared__ __align__(16) unsigned short XhL[BM * 256];  // 32 KB
    __shared__ __align__(16) unsigned short XlL[BM * 256];  // 32 KB
    __shared__ __align__(16) unsigned short PL [BN * 256];  // 16 KB
    __shared__ __align__(16) unsigned short AL [BN * 256];  // 16 KB
    __shared__ __align__(16) float Sx [BM][8];              // x2 partials
    __shared__ __align__(16) float Sp [BN][20];             // p2 partials (pad 20)
    __shared__ __align__(16) float Sa [BN][20];             // a2 partials
    __shared__ __align__(16) float Spa[BN][20];             // p.a partials

    const int t  = threadIdx.x;
    const int k0 = blockIdx.x * BN;
    const int b0 = blockIdx.y * BM;

    // ---- staging: threads 0-511 stage x (split hi/lo), 512-1023 stage p & a ----
    if (t < 512) {
        const int row = t & 63;
        const int cq  = t >> 6;                 // 0..7
        const float* g = x + (b0 + row) * D_;
        float4 v[8];
#pragma unroll
        for (int i = 0; i < 4; ++i) {           // hoist: issue all loads first
            const int c = cq + 8 * i;           // 16B chunk 0..31
            v[2 * i]     = *(const float4*)(g + c * 8);
            v[2 * i + 1] = *(const float4*)(g + c * 8 + 4);
        }
        float s0 = 0.f;
#pragma unroll
        for (int i = 0; i < 4; ++i) {
            const int c = cq + 8 * i;
            const float e[8] = {v[2*i].x, v[2*i].y, v[2*i].z, v[2*i].w,
                                v[2*i+1].x, v[2*i+1].y, v[2*i+1].z, v[2*i+1].w};
            unsigned int hp[4], lp[4];
#pragma unroll
            for (int j = 0; j < 4; ++j) {
                const float e0 = e[2 * j], e1 = e[2 * j + 1];
                const unsigned int hu = pk_bf16(e0, e1);
                const float h0 = __uint_as_float(hu << 16);
                const float h1 = __uint_as_float(hu & 0xFFFF0000u);
                hp[j] = hu;
                lp[j] = pk_bf16(e0 - h0, e1 - h1);
                s0 = fmaf(e0, e0, fmaf(e1, e1, s0));
            }
            const int idx = row * 256 + ((c ^ (row & 7)) << 3);
            *(uint4*)&XhL[idx] = make_uint4(hp[0], hp[1], hp[2], hp[3]);
            *(uint4*)&XlL[idx] = make_uint4(lp[0], lp[1], lp[2], lp[3]);
        }
        Sx[row][cq] = s0;
    } else {
        const int q   = t - 512;
        const int row = q & 31;
        const int cq  = q >> 5;                 // 0..15
        const float* gp = p + (k0 + row) * D_;
        const float* ga = a + (k0 + row) * D_;
        float4 pv[4], av[4];
#pragma unroll
        for (int i = 0; i < 2; ++i) {           // hoist: issue all loads first
            const int c = cq + 16 * i;          // 16B chunk 0..31
            pv[2 * i]     = *(const float4*)(gp + c * 8);
            pv[2 * i + 1] = *(const float4*)(gp + c * 8 + 4);
            av[2 * i]     = *(const float4*)(ga + c * 8);
            av[2 * i + 1] = *(const float4*)(ga + c * 8 + 4);
        }
        float sp2 = 0.f, sa2 = 0.f, spa = 0.f;
#pragma unroll
        for (int i = 0; i < 2; ++i) {
            const int c = cq + 16 * i;
            const float ep[8] = {pv[2*i].x, pv[2*i].y, pv[2*i].z, pv[2*i].w,
                                 pv[2*i+1].x, pv[2*i+1].y, pv[2*i+1].z, pv[2*i+1].w};
            const float ea[8] = {av[2*i].x, av[2*i].y, av[2*i].z, av[2*i].w,
                                 av[2*i+1].x, av[2*i+1].y, av[2*i+1].z, av[2*i+1].w};
            unsigned int wp[4], wa[4];
#pragma unroll
            for (int j = 0; j < 4; ++j) {
                const float pe0 = ep[2 * j], pe1 = ep[2 * j + 1];
                const float ae0 = ea[2 * j], ae1 = ea[2 * j + 1];
                wp[j] = pk_bf16(pe0, pe1);
                wa[j] = pk_bf16(ae0, ae1);
                sp2 = fmaf(pe0, pe0, fmaf(pe1, pe1, sp2));
                sa2 = fmaf(ae0, ae0, fmaf(ae1, ae1, sa2));
                spa = fmaf(pe0, ae0, fmaf(pe1, ae1, spa));
            }
            const int idx = row * 256 + ((c ^ (row & 7)) << 3);
            *(uint4*)&PL[idx] = make_uint4(wp[0], wp[1], wp[2], wp[3]);
            *(uint4*)&AL[idx] = make_uint4(wa[0], wa[1], wa[2], wa[3]);
        }
        Sp [row][cq] = sp2;
        Sa [row][cq] = sa2;
        Spa[row][cq] = spa;
    }

    __syncthreads();   // the only barrier
    if (t >= 512) return;   // waves 8-15 are staging-only

    // ---- MFMA: wave (wm, wn) owns 16x16 tile at (wm*16, wn*16) ----
    const int lane = t & 63;
    const int wave = t >> 6;                    // 0..7
    const int wm = wave & 3, wn = wave >> 2;
    const int m0 = wm * 16, n0 = wn * 16;
    const int lr = lane & 15, lg = lane >> 4;

    // 4 independent accumulator chains (hi/lo x D/A), summed after the loop
    floatx4 accDh = {0.f, 0.f, 0.f, 0.f};
    floatx4 accDl = {0.f, 0.f, 0.f, 0.f};
    floatx4 accAh = {0.f, 0.f, 0.f, 0.f};
    floatx4 accAl = {0.f, 0.f, 0.f, 0.f};

    const int xbase = (m0 + lr) * 256;
    const int pbase = (n0 + lr) * 256;
    const int sw    = lr & 7;
#pragma unroll
    for (int ks = 0; ks < 8; ++ks) {
        const int off = ((ks * 4 + lg) ^ sw) << 3;
        const short8 xh = *(const short8*)&XhL[xbase + off];
        const short8 xl = *(const short8*)&XlL[xbase + off];
        const short8 pw = *(const short8*)&PL [pbase + off];
        const short8 aw = *(const short8*)&AL [pbase + off];
        accDh = __builtin_amdgcn_mfma_f32_16x16x32_bf16(xh, pw, accDh, 0, 0, 0);
        accAh = __builtin_amdgcn_mfma_f32_16x16x32_bf16(xh, aw, accAh, 0, 0, 0);
        accDl = __builtin_amdgcn_mfma_f32_16x16x32_bf16(xl, pw, accDl, 0, 0, 0);
        accAl = __builtin_amdgcn_mfma_f32_16x16x32_bf16(xl, aw, accAl, 0, 0, 0);
    }

    // ---- epilogue: Ganea hyperbolic MLR logit ----
    // C/D layout (m89): col = lane&15, row = (lane>>4)*4 + reg
    const int kc = n0 + lr;
    float p2 = 0.f, a2 = 0.f, pa = 0.f;
#pragma unroll
    for (int j = 0; j < 4; ++j) {
        const float4 q0 = *(const float4*)&Sp [kc][4 * j];
        const float4 q1 = *(const float4*)&Sa [kc][4 * j];
        const float4 q2 = *(const float4*)&Spa[kc][4 * j];
        p2 += (q0.x + q0.y) + (q0.z + q0.w);
        a2 += (q1.x + q1.y) + (q1.z + q1.w);
        pa += (q2.x + q2.y) + (q2.z + q2.w);
    }
    const float beta = 1.f - p2;
    const float na   = beta * sqrtf(a2);
    const float lam  = 2.f / (beta + EPS_);
#pragma unroll
    for (int i = 0; i < 4; ++i) {
        const int r = m0 + lg * 4 + i;
        const float4 sx0 = *(const float4*)&Sx[r][0];
        const float4 sx1 = *(const float4*)&Sx[r][4];
        const float x2v = ((sx0.x + sx0.y) + (sx0.z + sx0.w))
                        + ((sx1.x + sx1.y) + (sx1.z + sx1.w));
        const float dt  = accDh[i] + accDl[i];
        const float xa  = accAh[i] + accAl[i];
        const float alpha = 1.f + x2v - 2.f * dt;
        const float rg    = 1.f / (1.f - 2.f * dt + p2 * x2v + EPS_);
        const float z2    = (alpha * alpha * p2 - 2.f * alpha * beta * dt
                             + beta * beta * x2v) * rg * rg;
        const float za    = beta * (beta * xa - alpha * pa) * rg;
        const float arg   = 2.f * za / ((1.f - z2) * na + EPS_);
        out[(b0 + r) * K_ + k0 + kc] = lam * na * fast_asinh(arg);
    }
}

extern "C" void kernel_launch(void* const* d_in, const int* in_sizes, int n_in,
                              void* d_out, int out_size, void* d_ws, size_t ws_size,
                              hipStream_t stream) {
    const float* x = (const float*)d_in[0];  // [512, 256]
    const float* p = (const float*)d_in[1];  // [1024, 256]
    const float* a = (const float*)d_in[2];  // [1024, 256]
    float* out = (float*)d_out;              // [512, 1024]

    dim3 grid(K_ / BN, B_ / BM);   // (32, 8) = 256 blocks, 1/CU
    dim3 block(1024);              // 16 waves: all stage, waves 0-7 compute
    hyp_mlr_mfma<<<grid, block, 0, stream>>>(x, p, a, out);
}